// Round 14
// baseline (153.411 us; speedup 1.0000x reference)
//
#include <hip/hip_runtime.h>
#include <cstdint>

#define T_DIM 1000
#define B_DIM 64
#define C_DIM 256
#define L_DIM 100
#define S_DIM (2 * L_DIM + 1) /* 201 */
#define NBLK (2 * B_DIM)      /* 64 CTC + 64 mean blocks */

typedef float f32x4 __attribute__((ext_vector_type(4)));

// DPP cross-lane (VALU-rate). wave_shr:1=0x138, row_shr:n=0x110|n,
// row_bcast:15=0x142, row_bcast:31=0x143. bound_ctrl=true -> invalid lanes read 0.
#define DPP_I(x, ctrl) __builtin_amdgcn_update_dpp(0, (x), (ctrl), 0xF, 0xF, true)
#define DPP_F(x, ctrl) __int_as_float(DPP_I(__float_as_int(x), (ctrl)))

// R14 structural ablation: the CTC block is ONE WAVE. No producers, no LDS,
// no barriers -- the only elements never removed across R1-R13's neutral
// results. Consumer pulls rp[0], rp[c1], rp[c3] per step DIRECTLY from
// global (L3-resident: mean blocks stream all of lp concurrently) via an
// 8-step-deep inline-asm pipeline with counted vmcnt waits (R4's proven
// lgkmcnt pattern, ported to vmcnt; m135: waits cover the oldest loads).
// Same exp on same bits, same step order, same renorm set -> bit-identical.
#define GLD(dst, voff) \
    asm volatile("global_load_dword %0, %1, %2" : "=v"(dst) : "v"(voff), "s"(lp))
#define WV(N) do { asm volatile("s_waitcnt vmcnt(" N ")"); __builtin_amdgcn_sched_barrier(0); } while (0)
#define ISSUE(s) do { GLD(g0_##s, o0); GLD(g1_##s, o1); GLD(g3_##s, o3); \
                      o0 += 65536u; o1 += 65536u; o3 += 65536u; } while (0)
// full-rate step: wait own 3 loads (21 = 24 in flight - 3 oldest), exp, step, refill
#define SFULL(s) do { WV("21"); \
        const float e0 = __expf(g0_##s), e1 = __expf(g1_##s), e3 = __expf(g3_##s); \
        step(e0, e1, e3); ISSUE(s); } while (0)
#define SLAST(s) do { WV("21"); \
        const float e0 = __expf(g0_##s), e1 = __expf(g1_##s), e3 = __expf(g3_##s); \
        step(e0, e1, e3); } while (0)
#define STAIL(s, N) do { WV(N); \
        const float e0 = __expf(g0_##s), e1 = __expf(g1_##s), e3 = __expf(g3_##s); \
        step(e0, e1, e3); } while (0)

// Wave-wide max of non-negative values; exact, order-independent.
__device__ __forceinline__ float wave_max_dpp(float x) {
    x = fmaxf(x, DPP_F(x, 0x111)); // row_shr:1
    x = fmaxf(x, DPP_F(x, 0x112)); // row_shr:2
    x = fmaxf(x, DPP_F(x, 0x114)); // row_shr:4
    x = fmaxf(x, DPP_F(x, 0x118)); // row_shr:8
    x = fmaxf(x, DPP_F(x, 0x142)); // row_bcast:15
    x = fmaxf(x, DPP_F(x, 0x143)); // row_bcast:31 -> lane 63 has wave max
    return __int_as_float(__builtin_amdgcn_readlane(__float_as_int(x), 63));
}

// Single kernel, 128 blocks x 512 threads.
//   blocks [0,B): CTC, wave 0 only (waves 1-7 exit): barrier-free 1-wave
//                 chain with deep global-load pipeline; loss -> atomicAdd ws[1].
//   blocks [B,2B): per-sample mean + focal (R13 form) -> atomicAdd ws[0].
//   last arriver (counter ws[2]): out = (F/(B*L)) * (Lo/B). Fence-free
//   protocol (R12 lesson: NO per-block __threadfence).
__global__ __launch_bounds__(512, 1) void ctc_fused(
        const float* __restrict__ lp,       // (T,B,C)
        const int* __restrict__ tgt,        // (B*L,)
        const int* __restrict__ il,         // (B,)
        const int* __restrict__ tl,         // (B,)
        float* __restrict__ ws,             // [0]=F [1]=Lo [2]=counter
        float* __restrict__ out) {          // scalar
    const int blk = blockIdx.x;
    const int tid = threadIdx.x;
    const uint32_t rstride = B_DIM * C_DIM;

    if (blk >= B_DIM) {
        // ---- mean + focal pass: one block per sample b (R13, passing) ----
        __shared__ float sums[8][C_DIM];
        __shared__ float meanp[C_DIM];
        __shared__ float focal[128];
        const int b = blk - B_DIM;
        const int lane = tid & 63;
        const int wv = tid >> 6;                 // 0..7
        const float* p = lp + (size_t)b * C_DIM + (lane << 2);
        f32x4 s = {0.f, 0.f, 0.f, 0.f};
#pragma unroll 5
        for (int t = wv; t < T_DIM; t += 8) {    // 125 rows per wave
            f32x4 v = *(const f32x4*)(p + (size_t)t * rstride);
            s.x += __expf(v.x); s.y += __expf(v.y);
            s.z += __expf(v.z); s.w += __expf(v.w);
        }
        *(f32x4*)&sums[wv][lane << 2] = s;
        __syncthreads();
        if (tid < C_DIM) {
            const float tot = sums[0][tid] + sums[1][tid] + sums[2][tid] + sums[3][tid]
                            + sums[4][tid] + sums[5][tid] + sums[6][tid] + sums[7][tid];
            meanp[tid] = tot * (1.0f / T_DIM);
        }
        __syncthreads();
        if (tid < L_DIM) {
            const float pv = meanp[tgt[b * L_DIM + tid]];
            const float w = 1.0f - pv;
            focal[tid] = w * w;
        }
        __syncthreads();
        if (tid < 64) {
            float fs = focal[tid] + ((tid + 64 < L_DIM) ? focal[tid + 64] : 0.f);
#pragma unroll
            for (int off = 32; off > 0; off >>= 1) fs += __shfl_down(fs, off, 64);
            if (tid == 0) atomicAdd(&ws[0], fs);  // device-scope
        }
    } else if (tid < 64) {
        // ---- CTC pass: ONE wave, no LDS, no barriers ----
        const int lane = tid;                    // 0..63
        const int b = blk;
        const int* trow = tgt + b * L_DIM;
        const int ilen = il[b];
        const int tlen = tl[b];

        const int i1 = 2 * lane;
        const int i3 = 2 * lane + 1;
        const int c1 = (i1 < L_DIM) ? trow[i1] : 0;
        const int c3 = (i3 < L_DIM) ? trow[i3] : 0;
        const int c1m = (i1 >= 1 && i1 - 1 < L_DIM) ? trow[i1 - 1] : -1;
        const float m1 = ((i1 >= 1) && (c1 != c1m)) ? 1.0f : 0.0f;
        const float m3 = (c3 != c1) ? 1.0f : 0.0f;

        // invalid states (s >= S) must be zeroed at each renorm
        const float f0 = (4 * lane + 0 < S_DIM) ? 1.0f : 0.0f;
        const float f1 = (4 * lane + 1 < S_DIM) ? 1.0f : 0.0f;
        const float f2 = (4 * lane + 2 < S_DIM) ? 1.0f : 0.0f;
        const float f3 = (4 * lane + 3 < S_DIM) ? 1.0f : 0.0f;

        const float* base = lp + (size_t)b * C_DIM;

        // t=0 init (bit-identical)
        float a0 = 0.f, a1 = 0.f, a2 = 0.f, a3 = 0.f;
        {
            float i0 = __expf(base[0]);
            float i1v = __expf(base[c1]);
            if (lane == 0) { a0 = i0; a1 = i1v; }
        }
        float ls = 0.f;

        // consumer step: absmax must stay 96.0.
        auto step = [&](float pb, float p1e, float p3e) {
            const float p3 = DPP_F(a3, 0x138); // prev lane's a3; lane0 -> 0
            const float a01 = a0 + a1;
            const float n0 = (a0 + p3) * pb;
            const float n1 = fmaf(m1, p3, a01) * p1e;
            const float n2 = (a2 + a1) * pb;
            const float n3 = (fmaf(m3, a1, a2) + a3) * p3e;
            a0 = n0; a1 = n1; a2 = n2; a3 = n3;
        };

#define RENORM() do {                                                       \
        a0 *= f0; a1 *= f1; a2 *= f2; a3 *= f3;                             \
        const float mx = wave_max_dpp(fmaxf(fmaxf(a0, a1), fmaxf(a2, a3))); \
        const float inv = __builtin_amdgcn_rcpf(mx);                        \
        ls -= __logf(inv);                                                  \
        a0 *= inv; a1 *= inv; a2 *= inv; a3 *= inv;                         \
    } while (0)

        if (ilen == T_DIM) {
            // fast path: flat 999-step chain, renorm at t%8==0 (t=8..992) --
            // EXACTLY the established renorm set.
            float g0_0, g0_1, g0_2, g0_3, g0_4, g0_5, g0_6, g0_7;
            float g1_0, g1_1, g1_2, g1_3, g1_4, g1_5, g1_6, g1_7;
            float g3_0, g3_1, g3_2, g3_3, g3_4, g3_5, g3_6, g3_7;
            const uint32_t bc = (uint32_t)b * C_DIM * 4u;
            uint32_t o0 = bc + 65536u;                       // t=1, c=0
            uint32_t o1 = bc + 65536u + ((uint32_t)c1 << 2); // t=1, c1
            uint32_t o3 = bc + 65536u + ((uint32_t)c3 << 2); // t=1, c3
            // prologue: t=1..8 in flight (24 loads)
            ISSUE(0); ISSUE(1); ISSUE(2); ISSUE(3);
            ISSUE(4); ISSUE(5); ISSUE(6); ISSUE(7);
            // bodies m=0..122: t=1..984, renorm at each t%8==0
            for (int m = 0; m < 123; ++m) {
                SFULL(0); SFULL(1); SFULL(2); SFULL(3);
                SFULL(4); SFULL(5); SFULL(6); SFULL(7);
                RENORM();
            }
            // body 123: t=985..992 (issues 993..999; t=992 none), renorm @992
            SFULL(0); SFULL(1); SFULL(2); SFULL(3);
            SFULL(4); SFULL(5); SFULL(6); SLAST(7);
            RENORM();
            // tail: t=993..999, draining waits
            STAIL(0, "18"); STAIL(1, "15"); STAIL(2, "12"); STAIL(3, "9");
            STAIL(4, "6");  STAIL(5, "3");  STAIL(6, "0");
        } else {
            // generic fallback (unused for this problem's inputs)
            for (int t = 1; t < ilen; ++t) {
                const float* rp = base + (size_t)t * rstride;
                step(__expf(rp[0]), __expf(rp[c1]), __expf(rp[c3]));
                if ((t & 7) == 0) RENORM();
            }
        }
#undef RENORM

        // final: ll = log(alpha[2tl] + alpha[2tl-1]) + ls
        const int s_hi = 2 * tlen;
        const int s_lo = 2 * tlen - 1;
        const int slot_hi = s_hi & 3, lane_hi = min(s_hi >> 2, 63);
        const int slot_lo = s_lo & 3, lane_lo = min(s_lo >> 2, 63);
        float chv = (slot_hi == 0) ? a0 : (slot_hi == 1) ? a1 : (slot_hi == 2) ? a2 : a3;
        float clv = (slot_lo == 0) ? a0 : (slot_lo == 1) ? a1 : (slot_lo == 2) ? a2 : a3;
        const float vh = __shfl(chv, lane_hi, 64);
        const float vl = __shfl(clv, lane_lo, 64);
        if (lane == 0) {
            const float s = vh + vl;
            const float loss = (s > 0.f) ? -(__logf(s) + ls) : 0.0f; // zero_infinity
            atomicAdd(&ws[1], loss);   // device-scope
        }
    }

    // ---- fence-free last-arriver finalize (tid0 of each block) ----
    if (tid == 0) {
        asm volatile("s_waitcnt vmcnt(0)"); // my own data-atomic is complete
        unsigned int* ctr = (unsigned int*)ws + 2;
        const unsigned int old = atomicAdd(ctr, 1u);
        if (old == NBLK - 1) {
            const float F = atomicAdd(&ws[0], 0.0f);   // atomic read
            const float Lo = atomicAdd(&ws[1], 0.0f);  // atomic read
            out[0] = (F / (float)(B_DIM * L_DIM)) * (Lo / (float)B_DIM);
        }
    }
}

extern "C" void kernel_launch(void* const* d_in, const int* in_sizes, int n_in,
                              void* d_out, int out_size, void* d_ws, size_t ws_size,
                              hipStream_t stream) {
    const float* lp = (const float*)d_in[0];
    const int* tgt = (const int*)d_in[1];
    const int* il = (const int*)d_in[2];
    const int* tl = (const int*)d_in[3];
    float* ws = (float*)d_ws;   // [0]=F [1]=Lo [2]=counter

    hipMemsetAsync(ws, 0, 3 * sizeof(float), stream);
    ctc_fused<<<dim3(NBLK), dim3(512), 0, stream>>>(
        lp, tgt, il, tl, ws, (float*)d_out);
}

// Round 17
// 133.522 us; speedup vs baseline: 1.1490x; 1.1490x over previous
//
#include <hip/hip_runtime.h>
#include <cstdint>

#define T_DIM 1000
#define B_DIM 64
#define C_DIM 256
#define L_DIM 100
#define S_DIM (2 * L_DIM + 1) /* 201 */
#define CH 32                 /* steps per chunk */
#define NPROD 7               /* producer waves (block = 8 waves) */
#define RPW 5                 /* ceil(CH/NPROD) rows per producer wave */
#define NBLK (2 * B_DIM)      /* 64 CTC + 64 mean blocks */

typedef float f32x4 __attribute__((ext_vector_type(4)));

// DPP cross-lane (VALU-rate). wave_shr:1=0x138, row_shr:n=0x110|n,
// row_bcast:15=0x142, row_bcast:31=0x143. bound_ctrl=true -> invalid lanes read 0.
#define DPP_I(x, ctrl) __builtin_amdgcn_update_dpp(0, (x), (ctrl), 0xF, 0xF, true)
#define DPP_F(x, ctrl) __int_as_float(DPP_I(__float_as_int(x), (ctrl)))

// R15 lesson (absmax 160 FAIL): the consumer's arithmetic DAG is frozen --
// deferred-renorm reassociation drifted past the bf16 output bucket (margin
// 96.0 vs 103.68). Only instruction ENCODING may change (R4/R11 precedent).
// R16 theory: consumer is ISSUE-bound at DVFS-sagged clock (~45cy/step of
// issue explains 57us at ~0.9GHz; consistent with R1-R14's total insensitivity
// to latency/conflict/barrier changes). Fix: TRANSPOSED emit layout ->
// 3x ds_read_b128 + 1 waitcnt per 4 STEPS (was 12x ds_read_b32 + 4 waits).
// Same values, same op order -> bit-identical; absmax must stay 96.0.
// (R17 = R16 resubmitted: container failed twice, kernel never measured.)
#define DSR4(dst, addr, OFF) \
    asm volatile("ds_read_b128 %0, %1 offset:" OFF : "=v"(dst) : "v"(addr))
#define ISSG(r, QOFF, POFF) do { DSR4(Q1##r, aq1, QOFF); DSR4(Q3##r, aq3, QOFF); \
                                 DSR4(PB##r, apb, POFF); } while (0)
#define W(N) do { asm volatile("s_waitcnt lgkmcnt(" N ")"); __builtin_amdgcn_sched_barrier(0); } while (0)
#define S4(r) do { step(PB##r.x, Q1##r.x, Q3##r.x); step(PB##r.y, Q1##r.y, Q3##r.y); \
                   step(PB##r.z, Q1##r.z, Q3##r.z); step(PB##r.w, Q1##r.w, Q3##r.w); } while (0)

// Wave-wide max of non-negative values; exact, order-independent.
__device__ __forceinline__ float wave_max_dpp(float x) {
    x = fmaxf(x, DPP_F(x, 0x111)); // row_shr:1
    x = fmaxf(x, DPP_F(x, 0x112)); // row_shr:2
    x = fmaxf(x, DPP_F(x, 0x114)); // row_shr:4
    x = fmaxf(x, DPP_F(x, 0x118)); // row_shr:8
    x = fmaxf(x, DPP_F(x, 0x142)); // row_bcast:15
    x = fmaxf(x, DPP_F(x, 0x143)); // row_bcast:31 -> lane 63 has wave max
    return __int_as_float(__builtin_amdgcn_readlane(__float_as_int(x), 63));
}

// Single kernel, 128 blocks x 512 threads (R13 layout, best passing: 135.5us).
//   blocks [0,B): CTC; consumer reads 4 steps per 3x ds_read_b128 from the
//                 transposed emit arrays; loss -> atomicAdd ws[1].
//   blocks [B,2B): per-sample mean + focal -> atomicAdd ws[0].
//   last arriver (counter ws[2]): out = (F/(B*L)) * (Lo/B). Fence-free
//   (R12 lesson: no per-block __threadfence).
__global__ __launch_bounds__(512, 1) void ctc_fused(
        const float* __restrict__ lp,       // (T,B,C)
        const int* __restrict__ tgt,        // (B*L,)
        const int* __restrict__ il,         // (B,)
        const int* __restrict__ tl,         // (B,)
        float* __restrict__ ws,             // [0]=F [1]=Lo [2]=counter
        float* __restrict__ out) {          // scalar
    const int blk = blockIdx.x;
    const int tid = threadIdx.x;
    const uint32_t rstride = B_DIM * C_DIM;

    if (blk >= B_DIM) {
        // ---- mean + focal pass: one block per sample b (R13, passing) ----
        __shared__ float sums[8][C_DIM];
        __shared__ float meanp[C_DIM];
        __shared__ float focal[128];
        const int b = blk - B_DIM;
        const int lane = tid & 63;
        const int wv = tid >> 6;                 // 0..7
        const float* p = lp + (size_t)b * C_DIM + (lane << 2);
        f32x4 s = {0.f, 0.f, 0.f, 0.f};
#pragma unroll 5
        for (int t = wv; t < T_DIM; t += 8) {    // 125 rows per wave
            f32x4 v = *(const f32x4*)(p + (size_t)t * rstride);
            s.x += __expf(v.x); s.y += __expf(v.y);
            s.z += __expf(v.z); s.w += __expf(v.w);
        }
        *(f32x4*)&sums[wv][lane << 2] = s;
        __syncthreads();
        if (tid < C_DIM) {
            const float tot = sums[0][tid] + sums[1][tid] + sums[2][tid] + sums[3][tid]
                            + sums[4][tid] + sums[5][tid] + sums[6][tid] + sums[7][tid];
            meanp[tid] = tot * (1.0f / T_DIM);
        }
        __syncthreads();
        if (tid < L_DIM) {
            const float pv = meanp[tgt[b * L_DIM + tid]];
            const float w = 1.0f - pv;
            focal[tid] = w * w;
        }
        __syncthreads();
        if (tid < 64) {
            float fs = focal[tid] + ((tid + 64 < L_DIM) ? focal[tid + 64] : 0.f);
#pragma unroll
            for (int off = 32; off > 0; off >>= 1) fs += __shfl_down(fs, off, 64);
            if (tid == 0) atomicAdd(&ws[0], fs);  // device-scope
        }
    } else {
        // ---- CTC pass ----
        // transposed emit: group g = d>>2, slot j = d&3.
        __shared__ __align__(16) float q1t[2][8][64][4];  // 16 KB
        __shared__ __align__(16) float q3t[2][8][64][4];  // 16 KB
        __shared__ __align__(16) float pbt[2][8][4];      // 256 B

        const int lane = tid & 63;
        const int wave = tid >> 6;
        const int b = blk;
        const int* trow = tgt + b * L_DIM;
        const int ilen = il[b];
        const int tlen = tl[b];

        const int i1 = 2 * lane;
        const int i3 = 2 * lane + 1;
        const int c1 = (i1 < L_DIM) ? trow[i1] : 0;
        const int c3 = (i3 < L_DIM) ? trow[i3] : 0;
        const int c1m = (i1 >= 1 && i1 - 1 < L_DIM) ? trow[i1 - 1] : -1;
        const float m1 = ((i1 >= 1) && (c1 != c1m)) ? 1.0f : 0.0f;
        const float m3 = (c3 != c1) ? 1.0f : 0.0f;

        // invalid states (s >= S) must be zeroed at each renorm
        const float f0 = (4 * lane + 0 < S_DIM) ? 1.0f : 0.0f;
        const float f1 = (4 * lane + 1 < S_DIM) ? 1.0f : 0.0f;
        const float f2 = (4 * lane + 2 < S_DIM) ? 1.0f : 0.0f;
        const float f3 = (4 * lane + 3 < S_DIM) ? 1.0f : 0.0f;

        const float* base = lp + (size_t)b * C_DIM;

        // t=0 init (bit-identical)
        float a0 = 0.f, a1 = 0.f, a2 = 0.f, a3 = 0.f;
        {
            float i0 = __expf(base[0]);
            float i1v = __expf(base[c1]);
            if (lane == 0 && wave == 0) { a0 = i0; a1 = i1v; }
        }
        float ls = 0.f;

        // producer: per row, 3 scattered COMPILER global loads, single anchor,
        // exp only needed values (R11/R13 passing form), transposed writes.
        auto produce = [&](int cc) {
            const int p = cc & 1;
            const int tstart = 1 + cc * CH;
            const int w = wave - 1;
            float v1[RPW], v3[RPW], v0[RPW];
#pragma unroll
            for (int k = 0; k < RPW; ++k) {
                const int d = w + NPROD * k;
                if (d < CH) {
                    int t = tstart + d; t = (t < ilen) ? t : (ilen - 1);
                    const float* rp = base + (size_t)t * rstride;
                    v1[k] = rp[c1];
                    v3[k] = rp[c3];
                    v0[k] = rp[0];
                } else {
                    v1[k] = 0.f; v3[k] = 0.f; v0[k] = 0.f;
                }
            }
            asm volatile("" : "+v"(v1[0]), "+v"(v1[1]), "+v"(v1[2]), "+v"(v1[3]), "+v"(v1[4]),
                              "+v"(v3[0]), "+v"(v3[1]), "+v"(v3[2]), "+v"(v3[3]), "+v"(v3[4]),
                              "+v"(v0[0]), "+v"(v0[1]), "+v"(v0[2]), "+v"(v0[3]), "+v"(v0[4]));
#pragma unroll
            for (int k = 0; k < RPW; ++k) {
                const int d = w + NPROD * k;
                if (d < CH) {
                    const float e1 = __expf(v1[k]);
                    const float e3 = __expf(v3[k]);
                    const float e0 = __expf(v0[k]);
                    q1t[p][d >> 2][lane][d & 3] = e1;
                    q3t[p][d >> 2][lane][d & 3] = e3;
                    if (lane == 0) pbt[p][d >> 2][d & 3] = e0;
                }
            }
        };

        // consumer step: inputs already exp'd; absmax must stay 96.0.
        auto step = [&](float pb, float p1e, float p3e) {
            const float p3 = DPP_F(a3, 0x138); // prev lane's a3; lane0 -> 0
            const float a01 = a0 + a1;
            const float n0 = (a0 + p3) * pb;
            const float n1 = fmaf(m1, p3, a01) * p1e;
            const float n2 = (a2 + a1) * pb;
            const float n3 = (fmaf(m3, a1, a2) + a3) * p3e;
            a0 = n0; a1 = n1; a2 = n2; a3 = n3;
        };

#define RENORM() do {                                                       \
        a0 *= f0; a1 *= f1; a2 *= f2; a3 *= f3;                             \
        const float mx = wave_max_dpp(fmaxf(fmaxf(a0, a1), fmaxf(a2, a3))); \
        const float inv = __builtin_amdgcn_rcpf(mx);                        \
        ls -= __logf(inv);                                                  \
        a0 *= inv; a1 *= inv; a2 *= inv; a3 *= inv;                         \
    } while (0)

        // consume chunk cc; renorm after groups 1,3,5,7 (d=7,15,23,31) --
        // EXACTLY the established renorm set. 2-group-deep b128 pipeline.
        auto consume = [&](int cc) {
            const int p = cc & 1;
            const int tstart = 1 + cc * CH;
            if (tstart + CH <= ilen) {
                uint32_t aq1 = (uint32_t)(uintptr_t)(&q1t[0][0][0][0])
                             + (uint32_t)(p * 8192) + ((uint32_t)lane << 4);
                uint32_t aq3 = (uint32_t)(uintptr_t)(&q3t[0][0][0][0])
                             + (uint32_t)(p * 8192) + ((uint32_t)lane << 4);
                uint32_t apb = (uint32_t)(uintptr_t)(&pbt[0][0][0])
                             + (uint32_t)(p * 128);          // uniform -> bcast
                f32x4 Q1A, Q3A, PBA, Q1B, Q3B, PBB;
                ISSG(A, "0", "0"); ISSG(B, "1024", "16");     // g0,g1 in flight
                W("3"); S4(A); ISSG(A, "2048", "32");         // g0 (d=0..3)
                W("3"); S4(B); RENORM(); ISSG(B, "3072", "48"); // g1 (d=7 ren)
                W("3"); S4(A); ISSG(A, "4096", "64");         // g2
                W("3"); S4(B); RENORM(); ISSG(B, "5120", "80"); // g3 (d=15)
                W("3"); S4(A); ISSG(A, "6144", "96");         // g4
                W("3"); S4(B); RENORM(); ISSG(B, "7168", "112"); // g5 (d=23)
                W("3"); S4(A);                                // g6
                W("0"); S4(B); RENORM();                      // g7 (d=31)
            } else {
                // tail chunk (7 steps for T=1000): point-of-use form
#pragma unroll
                for (int d = 0; d < CH; ++d) {
                    if (tstart + d < ilen) {
                        step(pbt[p][d >> 2][d & 3],
                             q1t[p][d >> 2][lane][d & 3],
                             q3t[p][d >> 2][lane][d & 3]);
                        if ((d & 7) == 7) RENORM();
                    }
                }
            }
        };

        const int nchunks = (ilen - 1 + CH - 1) / CH;
        if (wave != 0) produce(0);
        __syncthreads();
        if (wave == 0) __builtin_amdgcn_s_setprio(1);
        for (int c = 0; c < nchunks; ++c) {
            if (wave != 0) produce(c + 1);
            else consume(c);
            __syncthreads();
        }
        if (wave == 0) __builtin_amdgcn_s_setprio(0);
#undef RENORM

        if (wave == 0) {
            // final: ll = log(alpha[2tl] + alpha[2tl-1]) + ls
            const int s_hi = 2 * tlen;
            const int s_lo = 2 * tlen - 1;
            const int slot_hi = s_hi & 3, lane_hi = min(s_hi >> 2, 63);
            const int slot_lo = s_lo & 3, lane_lo = min(s_lo >> 2, 63);
            float chv = (slot_hi == 0) ? a0 : (slot_hi == 1) ? a1 : (slot_hi == 2) ? a2 : a3;
            float clv = (slot_lo == 0) ? a0 : (slot_lo == 1) ? a1 : (slot_lo == 2) ? a2 : a3;
            const float vh = __shfl(chv, lane_hi, 64);
            const float vl = __shfl(clv, lane_lo, 64);
            if (lane == 0) {
                const float s = vh + vl;
                const float loss = (s > 0.f) ? -(__logf(s) + ls) : 0.0f; // zero_infinity
                atomicAdd(&ws[1], loss);   // device-scope
            }
        }
    }

    // ---- fence-free last-arriver finalize (tid0 of each block) ----
    if (tid == 0) {
        asm volatile("s_waitcnt vmcnt(0)"); // my own data-atomic is complete
        unsigned int* ctr = (unsigned int*)ws + 2;
        const unsigned int old = atomicAdd(ctr, 1u);
        if (old == NBLK - 1) {
            const float F = atomicAdd(&ws[0], 0.0f);   // atomic read
            const float Lo = atomicAdd(&ws[1], 0.0f);  // atomic read
            out[0] = (F / (float)(B_DIM * L_DIM)) * (Lo / (float)B_DIM);
        }
    }
}

extern "C" void kernel_launch(void* const* d_in, const int* in_sizes, int n_in,
                              void* d_out, int out_size, void* d_ws, size_t ws_size,
                              hipStream_t stream) {
    const float* lp = (const float*)d_in[0];
    const int* tgt = (const int*)d_in[1];
    const int* il = (const int*)d_in[2];
    const int* tl = (const int*)d_in[3];
    float* ws = (float*)d_ws;   // [0]=F [1]=Lo [2]=counter

    hipMemsetAsync(ws, 0, 3 * sizeof(float), stream);
    ctc_fused<<<dim3(NBLK), dim3(512), 0, stream>>>(
        lp, tgt, il, tl, ws, (float*)d_out);
}